// Round 1
// baseline (230.721 us; speedup 1.0000x reference)
//
#include <hip/hip_runtime.h>
#include <cstdint>
#include <cstddef>

// Problem constants (match reference)
#define BATCH 32
#define NGT   32
#define NA    8732
#define NCLS  81
#define THR   0.4f

#define CH1 16                         // kernel1 anchor chunks
#define CS1 ((NA + CH1 - 1) / CH1)     // 546
#define NC3 32                         // kernel3 chunks
#define CS3 ((NA + NC3 - 1) / NC3)     // 273

// ---------------- k0: init packed prior accumulators ----------------
__global__ void k0_init(unsigned long long* __restrict__ prior_pack) {
    int t = blockIdx.x * blockDim.x + threadIdx.x;
    if (t < BATCH * NGT) prior_pack[t] = 0ULL;
}

// ---------------- k1: IoU, per-anchor max/argmax over gts, per-gt packed max over anchors
__global__ __launch_bounds__(256) void k1_iou(
    const float* __restrict__ tar_bbs,   // [B][N][4]
    const float* __restrict__ anchors,   // [A][4]
    float* __restrict__ gt_ov,           // [B][A]
    int*   __restrict__ gt_idx,          // [B][A]
    unsigned long long* __restrict__ prior_pack) // [B][N]
{
    const int b   = blockIdx.y;
    const int c   = blockIdx.x;
    const int tid = threadIdx.x;
    const int i   = tid & 31;   // gt index
    const int s   = tid >> 5;   // anchor slot group (0..7)

    const float4 tb = reinterpret_cast<const float4*>(tar_bbs)[b * NGT + i];
    const float area_i = (tb.z - tb.x) * (tb.w - tb.y);

    unsigned long long best = 0ULL;
    const int start = c * CS1;
    const int end   = (start + CS1 < NA) ? (start + CS1) : NA;

    for (int a = start + s; a < end; a += 8) {
        const float4 an = reinterpret_cast<const float4*>(anchors)[a];
        const float area_a = (an.z - an.x) * (an.w - an.y);
        const float ltx = fmaxf(tb.x, an.x), lty = fmaxf(tb.y, an.y);
        const float rbx = fminf(tb.z, an.z), rby = fminf(tb.w, an.w);
        const float w = fmaxf(rbx - ltx, 0.f), h = fmaxf(rby - lty, 0.f);
        const float inter = w * h;
        const float iou = inter / (area_i + area_a - inter);

        // per-gt best anchor: pack (iou_bits, ~a) so ties -> smallest a
        unsigned long long p =
            (((unsigned long long)__float_as_uint(iou)) << 32) | (unsigned)(~(unsigned)a);
        best = (p > best) ? p : best;

        // reduce over the 32-lane gt group: max iou, first (smallest) gt on tie
        float v = iou; int vi = i;
        #pragma unroll
        for (int off = 16; off >= 1; off >>= 1) {
            float v2 = __shfl_xor(v, off);
            int   i2 = __shfl_xor(vi, off);
            if (v2 > v || (v2 == v && i2 < vi)) { v = v2; vi = i2; }
        }
        if (i == 0) {
            gt_ov [(size_t)b * NA + a] = v;
            gt_idx[(size_t)b * NA + a] = vi;
        }
    }

    __shared__ unsigned long long lds[256];
    lds[tid] = best;
    __syncthreads();
    if (tid < NGT) {
        unsigned long long m = 0ULL;
        #pragma unroll
        for (int ss = 0; ss < 8; ++ss) {
            unsigned long long q = lds[ss * 32 + tid];
            m = (q > m) ? q : m;
        }
        atomicMax(&prior_pack[b * NGT + tid], m);
    }
}

// ---------------- k2: apply prior scatter (1.99) + forced gt_idx override
__global__ void k2_force(
    const unsigned long long* __restrict__ prior_pack,
    float* __restrict__ gt_ov, int* __restrict__ gt_idx)
{
    const int b = blockIdx.x;
    const int i = threadIdx.x; // 0..31
    __shared__ int pa[NGT];
    const unsigned a = ~(unsigned)(prior_pack[b * NGT + i] & 0xFFFFFFFFULL);
    pa[i] = (int)a;
    __syncthreads();
    int m = i;
    #pragma unroll
    for (int j = 0; j < NGT; ++j)
        if (pa[j] == (int)a && j > m) m = j;
    gt_ov [(size_t)b * NA + a] = 1.99f;
    gt_idx[(size_t)b * NA + a] = m;
}

// ---------------- k3: main loss pass (CE over 81 classes + L1 loc for positives)
__global__ __launch_bounds__(256) void k3_loss(
    const float* __restrict__ pred_bbs,   // [B][A][4]
    const float* __restrict__ pred_cs,    // [B][A][C]
    const float* __restrict__ tar_bbs,    // [B][N][4]
    const int*   __restrict__ tar_c,      // [B][N]
    const float* __restrict__ anchors,    // [A][4]
    const float* __restrict__ grid_size,  // [A]
    const float* __restrict__ gt_ov,
    const int*   __restrict__ gt_idx,
    float* __restrict__ loc_part, float* __restrict__ ce_part, int* __restrict__ np_part)
{
    const int b   = blockIdx.y;
    const int c   = blockIdx.x;
    const int tid = threadIdx.x;

    __shared__ float4 tb_s[NGT];
    __shared__ int    tc_s[NGT];
    if (tid < NGT) {
        tb_s[tid] = reinterpret_cast<const float4*>(tar_bbs)[b * NGT + tid];
        tc_s[tid] = tar_c[b * NGT + tid];
    }
    __syncthreads();

    float loc = 0.f, ce = 0.f; int npos = 0;
    const int start = c * CS3;
    const int end   = (start + CS3 < NA) ? (start + CS3) : NA;

    for (int a = start + tid; a < end; a += 256) {
        const float ov = gt_ov [(size_t)b * NA + a];
        const int   gi = gt_idx[(size_t)b * NA + a];
        const bool pos = ov > THR;

        const float* row = pred_cs + ((size_t)b * NA + a) * NCLS;
        float mx = row[0];
        #pragma unroll 8
        for (int j = 1; j < NCLS; ++j) mx = fmaxf(mx, row[j]);
        float se = 0.f;
        #pragma unroll 8
        for (int j = 0; j < NCLS; ++j) se += expf(row[j] - mx);
        const float lse = mx + logf(se);

        const int label = pos ? tc_s[gi] : 0;
        ce += lse - row[label];

        if (pos) {
            const float4 pb = reinterpret_cast<const float4*>(pred_bbs)[(size_t)b * NA + a];
            const float4 an = reinterpret_cast<const float4*>(anchors)[a];
            const float g = grid_size[a] * 0.5f;
            const float tx = tanhf(pb.x), ty = tanhf(pb.y), tz = tanhf(pb.z), tw = tanhf(pb.w);
            const float ax = an.x + tx * g, ay = an.y + ty * g;
            const float az = an.z + tz * g, aw = an.w + tw * g;
            const float4 mb = tb_s[gi];
            loc += fabsf(ax - mb.x) + fabsf(ay - mb.y) + fabsf(az - mb.z) + fabsf(aw - mb.w);
            npos++;
        }
    }

    // block reduce (64-lane wave shuffle, then LDS across 4 waves)
    #pragma unroll
    for (int off = 32; off >= 1; off >>= 1) {
        loc  += __shfl_down(loc,  off);
        ce   += __shfl_down(ce,   off);
        npos += __shfl_down(npos, off);
    }
    __shared__ float lred[4], cred[4];
    __shared__ int   nred[4];
    const int wid = tid >> 6;
    if ((tid & 63) == 0) { lred[wid] = loc; cred[wid] = ce; nred[wid] = npos; }
    __syncthreads();
    if (tid == 0) {
        float L = 0.f, Ce = 0.f; int Np = 0;
        #pragma unroll
        for (int wq = 0; wq < 4; ++wq) { L += lred[wq]; Ce += cred[wq]; Np += nred[wq]; }
        loc_part[b * NC3 + c] = L;
        ce_part [b * NC3 + c] = Ce;
        np_part [b * NC3 + c] = Np;
    }
}

// ---------------- k4: fixed-order final reduction -> scalar
__global__ void k4_final(const float* __restrict__ loc_part,
                         const float* __restrict__ ce_part,
                         const int*   __restrict__ np_part,
                         float* __restrict__ out)
{
    const int t = threadIdx.x; // 64 threads
    float loss = 0.f;
    if (t < BATCH) {
        float L = 0.f, Ce = 0.f; int Np = 0;
        for (int c = 0; c < NC3; ++c) {
            L  += loc_part[t * NC3 + c];
            Ce += ce_part [t * NC3 + c];
            Np += np_part [t * NC3 + c];
        }
        const int denom_i = (Np * 4 > 1) ? Np * 4 : 1;
        loss = L / (float)denom_i + Ce / (float)NA;
    }
    #pragma unroll
    for (int off = 32; off >= 1; off >>= 1) loss += __shfl_down(loss, off);
    if (t == 0) out[0] = loss;
}

extern "C" void kernel_launch(void* const* d_in, const int* in_sizes, int n_in,
                              void* d_out, int out_size, void* d_ws, size_t ws_size,
                              hipStream_t stream) {
    const float* pred_bbs  = (const float*)d_in[0];
    const float* pred_cs   = (const float*)d_in[1];
    const float* tar_bbs   = (const float*)d_in[2];
    const int*   tar_c     = (const int*)  d_in[3];
    const float* anchors   = (const float*)d_in[4];
    const float* grid_size = (const float*)d_in[5];
    float* out = (float*)d_out;

    char* ws = (char*)d_ws;
    float* gt_ov = (float*)ws;                              ws += sizeof(float) * BATCH * NA;
    int*   gt_idx = (int*)ws;                               ws += sizeof(int)   * BATCH * NA;
    unsigned long long* prior = (unsigned long long*)ws;    ws += sizeof(unsigned long long) * BATCH * NGT;
    float* loc_part = (float*)ws;                           ws += sizeof(float) * BATCH * NC3;
    float* ce_part  = (float*)ws;                           ws += sizeof(float) * BATCH * NC3;
    int*   np_part  = (int*)ws;                             ws += sizeof(int)   * BATCH * NC3;

    hipLaunchKernelGGL(k0_init, dim3(4), dim3(256), 0, stream, prior);
    hipLaunchKernelGGL(k1_iou, dim3(CH1, BATCH), dim3(256), 0, stream,
                       tar_bbs, anchors, gt_ov, gt_idx, prior);
    hipLaunchKernelGGL(k2_force, dim3(BATCH), dim3(32), 0, stream,
                       prior, gt_ov, gt_idx);
    hipLaunchKernelGGL(k3_loss, dim3(NC3, BATCH), dim3(256), 0, stream,
                       pred_bbs, pred_cs, tar_bbs, tar_c, anchors, grid_size,
                       gt_ov, gt_idx, loc_part, ce_part, np_part);
    hipLaunchKernelGGL(k4_final, dim3(1), dim3(64), 0, stream,
                       loc_part, ce_part, np_part, out);
}

// Round 2
// 112.309 us; speedup vs baseline: 2.0543x; 2.0543x over previous
//
#include <hip/hip_runtime.h>
#include <cstdint>
#include <cstddef>

// Problem constants (match reference)
#define BATCH 32
#define NGT   32
#define NA    8732
#define NCLS  81
#define THR   0.4f

#define CH1 16                         // kernel1 anchor chunks
#define CS1 ((NA + CH1 - 1) / CH1)     // 546
#define TILE3 128                      // kernel3 anchors per block
#define NC3 ((NA + TILE3 - 1) / TILE3) // 69 chunks (last = 28 rows)

// ---------------- k0: init packed prior accumulators ----------------
__global__ void k0_init(unsigned long long* __restrict__ prior_pack) {
    int t = blockIdx.x * blockDim.x + threadIdx.x;
    if (t < BATCH * NGT) prior_pack[t] = 0ULL;
}

// ---------------- k1: IoU, per-anchor max/argmax over gts, per-gt packed max over anchors
__global__ __launch_bounds__(256) void k1_iou(
    const float* __restrict__ tar_bbs,   // [B][N][4]
    const float* __restrict__ anchors,   // [A][4]
    float* __restrict__ gt_ov,           // [B][A]
    int*   __restrict__ gt_idx,          // [B][A]
    unsigned long long* __restrict__ prior_pack) // [B][N]
{
    const int b   = blockIdx.y;
    const int c   = blockIdx.x;
    const int tid = threadIdx.x;
    const int i   = tid & 31;   // gt index
    const int s   = tid >> 5;   // anchor slot group (0..7)

    const float4 tb = reinterpret_cast<const float4*>(tar_bbs)[b * NGT + i];
    const float area_i = (tb.z - tb.x) * (tb.w - tb.y);

    unsigned long long best = 0ULL;
    const int start = c * CS1;
    const int end   = (start + CS1 < NA) ? (start + CS1) : NA;

    for (int a = start + s; a < end; a += 8) {
        const float4 an = reinterpret_cast<const float4*>(anchors)[a];
        const float area_a = (an.z - an.x) * (an.w - an.y);
        const float ltx = fmaxf(tb.x, an.x), lty = fmaxf(tb.y, an.y);
        const float rbx = fminf(tb.z, an.z), rby = fminf(tb.w, an.w);
        const float w = fmaxf(rbx - ltx, 0.f), h = fmaxf(rby - lty, 0.f);
        const float inter = w * h;
        const float iou = inter / (area_i + area_a - inter);

        // per-gt best anchor: pack (iou_bits, ~a) so ties -> smallest a
        unsigned long long p =
            (((unsigned long long)__float_as_uint(iou)) << 32) | (unsigned)(~(unsigned)a);
        best = (p > best) ? p : best;

        // reduce over the 32-lane gt group: max iou, first (smallest) gt on tie
        float v = iou; int vi = i;
        #pragma unroll
        for (int off = 16; off >= 1; off >>= 1) {
            float v2 = __shfl_xor(v, off);
            int   i2 = __shfl_xor(vi, off);
            if (v2 > v || (v2 == v && i2 < vi)) { v = v2; vi = i2; }
        }
        if (i == 0) {
            gt_ov [(size_t)b * NA + a] = v;
            gt_idx[(size_t)b * NA + a] = vi;
        }
    }

    __shared__ unsigned long long lds[256];
    lds[tid] = best;
    __syncthreads();
    if (tid < NGT) {
        unsigned long long m = 0ULL;
        #pragma unroll
        for (int ss = 0; ss < 8; ++ss) {
            unsigned long long q = lds[ss * 32 + tid];
            m = (q > m) ? q : m;
        }
        atomicMax(&prior_pack[b * NGT + tid], m);
    }
}

// ---------------- k2: apply prior scatter (1.99) + forced gt_idx override
__global__ void k2_force(
    const unsigned long long* __restrict__ prior_pack,
    float* __restrict__ gt_ov, int* __restrict__ gt_idx)
{
    const int b = blockIdx.x;
    const int i = threadIdx.x; // 0..31
    __shared__ int pa[NGT];
    const unsigned a = ~(unsigned)(prior_pack[b * NGT + i] & 0xFFFFFFFFULL);
    pa[i] = (int)a;
    __syncthreads();
    int m = i;
    #pragma unroll
    for (int j = 0; j < NGT; ++j)
        if (pa[j] == (int)a && j > m) m = j;
    gt_ov [(size_t)b * NA + a] = 1.99f;
    gt_idx[(size_t)b * NA + a] = m;
}

// ---------------- k3: main loss pass. pred_cs tile staged via LDS with
// coalesced float4 loads; softmax computed single-HBM-pass from LDS.
__global__ __launch_bounds__(256) void k3_loss(
    const float* __restrict__ pred_bbs,   // [B][A][4]
    const float* __restrict__ pred_cs,    // [B][A][C]
    const float* __restrict__ tar_bbs,    // [B][N][4]
    const int*   __restrict__ tar_c,      // [B][N]
    const float* __restrict__ anchors,    // [A][4]
    const float* __restrict__ grid_size,  // [A]
    const float* __restrict__ gt_ov,
    const int*   __restrict__ gt_idx,
    float* __restrict__ loc_part, float* __restrict__ ce_part, int* __restrict__ np_part)
{
    const int b   = blockIdx.y;
    const int c   = blockIdx.x;
    const int tid = threadIdx.x;
    const int a0  = c * TILE3;
    const int rows = (a0 + TILE3 <= NA) ? TILE3 : (NA - a0);

    __shared__ __align__(16) float row_s[TILE3 * NCLS];   // 41472 B
    __shared__ float4 tb_s[NGT];
    __shared__ int    tc_s[NGT];

    if (tid < NGT) {
        tb_s[tid] = reinterpret_cast<const float4*>(tar_bbs)[b * NGT + tid];
        tc_s[tid] = tar_c[b * NGT + tid];
    }

    // ---- coalesced tile load: base offset (b*NA + a0)*81 is a multiple of
    // 4 floats (proven for TILE3=128), and rows*81 is divisible by 4.
    {
        const float4* src = reinterpret_cast<const float4*>(
            pred_cs + ((size_t)b * NA + a0) * NCLS);
        float4* dst = reinterpret_cast<float4*>(row_s);
        const int nvec = rows * NCLS / 4;  // 2592 full tile, 567 tail
        for (int t = tid; t < nvec; t += 256) dst[t] = src[t];
    }
    __syncthreads();

    float loc = 0.f, ce = 0.f; int npos = 0;

    if (tid < rows) {
        const int a = a0 + tid;
        const float* row = row_s + tid * NCLS;   // stride 81 (odd) -> no bank conflict

        float mx = row[0];
        #pragma unroll 8
        for (int j = 1; j < NCLS; ++j) mx = fmaxf(mx, row[j]);
        float se = 0.f;
        #pragma unroll 8
        for (int j = 0; j < NCLS; ++j) se += expf(row[j] - mx);
        const float lse = mx + logf(se);

        const float ov = gt_ov [(size_t)b * NA + a];
        const int   gi = gt_idx[(size_t)b * NA + a];
        const bool pos = ov > THR;

        const int label = pos ? tc_s[gi] : 0;
        ce = lse - row[label];

        if (pos) {
            const float4 pb = reinterpret_cast<const float4*>(pred_bbs)[(size_t)b * NA + a];
            const float4 an = reinterpret_cast<const float4*>(anchors)[a];
            const float g = grid_size[a] * 0.5f;
            const float tx = tanhf(pb.x), ty = tanhf(pb.y), tz = tanhf(pb.z), tw = tanhf(pb.w);
            const float ax = an.x + tx * g, ay = an.y + ty * g;
            const float az = an.z + tz * g, aw = an.w + tw * g;
            const float4 mb = tb_s[gi];
            loc = fabsf(ax - mb.x) + fabsf(ay - mb.y) + fabsf(az - mb.z) + fabsf(aw - mb.w);
            npos = 1;
        }
    }

    // block reduce (64-lane wave shuffle, then LDS across 4 waves)
    #pragma unroll
    for (int off = 32; off >= 1; off >>= 1) {
        loc  += __shfl_down(loc,  off);
        ce   += __shfl_down(ce,   off);
        npos += __shfl_down(npos, off);
    }
    __shared__ float lred[4], cred[4];
    __shared__ int   nred[4];
    const int wid = tid >> 6;
    if ((tid & 63) == 0) { lred[wid] = loc; cred[wid] = ce; nred[wid] = npos; }
    __syncthreads();
    if (tid == 0) {
        float L = 0.f, Ce = 0.f; int Np = 0;
        #pragma unroll
        for (int wq = 0; wq < 4; ++wq) { L += lred[wq]; Ce += cred[wq]; Np += nred[wq]; }
        loc_part[b * NC3 + c] = L;
        ce_part [b * NC3 + c] = Ce;
        np_part [b * NC3 + c] = Np;
    }
}

// ---------------- k4: fixed-order final reduction -> scalar
__global__ void k4_final(const float* __restrict__ loc_part,
                         const float* __restrict__ ce_part,
                         const int*   __restrict__ np_part,
                         float* __restrict__ out)
{
    const int t = threadIdx.x; // 64 threads
    float loss = 0.f;
    if (t < BATCH) {
        float L = 0.f, Ce = 0.f; int Np = 0;
        for (int c = 0; c < NC3; ++c) {
            L  += loc_part[t * NC3 + c];
            Ce += ce_part [t * NC3 + c];
            Np += np_part [t * NC3 + c];
        }
        const int denom_i = (Np * 4 > 1) ? Np * 4 : 1;
        loss = L / (float)denom_i + Ce / (float)NA;
    }
    #pragma unroll
    for (int off = 32; off >= 1; off >>= 1) loss += __shfl_down(loss, off);
    if (t == 0) out[0] = loss;
}

extern "C" void kernel_launch(void* const* d_in, const int* in_sizes, int n_in,
                              void* d_out, int out_size, void* d_ws, size_t ws_size,
                              hipStream_t stream) {
    const float* pred_bbs  = (const float*)d_in[0];
    const float* pred_cs   = (const float*)d_in[1];
    const float* tar_bbs   = (const float*)d_in[2];
    const int*   tar_c     = (const int*)  d_in[3];
    const float* anchors   = (const float*)d_in[4];
    const float* grid_size = (const float*)d_in[5];
    float* out = (float*)d_out;

    char* ws = (char*)d_ws;
    float* gt_ov = (float*)ws;                              ws += sizeof(float) * BATCH * NA;
    int*   gt_idx = (int*)ws;                               ws += sizeof(int)   * BATCH * NA;
    unsigned long long* prior = (unsigned long long*)ws;    ws += sizeof(unsigned long long) * BATCH * NGT;
    float* loc_part = (float*)ws;                           ws += sizeof(float) * BATCH * NC3;
    float* ce_part  = (float*)ws;                           ws += sizeof(float) * BATCH * NC3;
    int*   np_part  = (int*)ws;                             ws += sizeof(int)   * BATCH * NC3;

    hipLaunchKernelGGL(k0_init, dim3(4), dim3(256), 0, stream, prior);
    hipLaunchKernelGGL(k1_iou, dim3(CH1, BATCH), dim3(256), 0, stream,
                       tar_bbs, anchors, gt_ov, gt_idx, prior);
    hipLaunchKernelGGL(k2_force, dim3(BATCH), dim3(32), 0, stream,
                       prior, gt_ov, gt_idx);
    hipLaunchKernelGGL(k3_loss, dim3(NC3, BATCH), dim3(256), 0, stream,
                       pred_bbs, pred_cs, tar_bbs, tar_c, anchors, grid_size,
                       gt_ov, gt_idx, loc_part, ce_part, np_part);
    hipLaunchKernelGGL(k4_final, dim3(1), dim3(64), 0, stream,
                       loc_part, ce_part, np_part, out);
}

// Round 3
// 101.585 us; speedup vs baseline: 2.2712x; 1.1056x over previous
//
#include <hip/hip_runtime.h>
#include <cstdint>
#include <cstddef>

// Problem constants (match reference)
#define BATCH 32
#define NGT   32
#define NA    8732
#define NCLS  81
#define THR   0.4f

#define K1SPAN 512                       // anchors per k1 block (2 per thread)
#define CH1 ((NA + K1SPAN - 1) / K1SPAN) // 18
#define TILE3 96                         // kernel3 anchors per block
#define NC3 ((NA + TILE3 - 1) / TILE3)   // 91 chunks (last = 92 rows)

// ---------------- k0: init packed prior accumulators ----------------
__global__ void k0_init(unsigned long long* __restrict__ prior_pack) {
    int t = blockIdx.x * blockDim.x + threadIdx.x;
    if (t < BATCH * NGT) prior_pack[t] = 0ULL;
}

// ---------------- k1: IoU. Thread owns anchors; gt loop fully unrolled in
// registers (no per-anchor shuffles). Per-gt best reduced once per block.
__global__ __launch_bounds__(256) void k1_iou(
    const float* __restrict__ tar_bbs,   // [B][N][4]
    const float* __restrict__ anchors,   // [A][4]
    float* __restrict__ gt_ov,           // [B][A]
    int*   __restrict__ gt_idx,          // [B][A]
    unsigned long long* __restrict__ prior_pack) // [B][N]
{
    const int b   = blockIdx.y;
    const int c   = blockIdx.x;
    const int tid = threadIdx.x;

    __shared__ float4 tb_s[NGT];
    __shared__ float  ar_s[NGT];
    if (tid < NGT) {
        const float4 t = reinterpret_cast<const float4*>(tar_bbs)[b * NGT + tid];
        tb_s[tid] = t;
        ar_s[tid] = (t.z - t.x) * (t.w - t.y);
    }
    __syncthreads();

    float best[NGT];   // per-gt best iou over this thread's anchors
    int   bestA[NGT];
    #pragma unroll
    for (int j = 0; j < NGT; ++j) { best[j] = -1.f; bestA[j] = 0; }

    const int a0 = c * K1SPAN;
    #pragma unroll
    for (int k = 0; k < K1SPAN / 256; ++k) {
        const int a = a0 + k * 256 + tid;
        if (a < NA) {
            const float4 an = reinterpret_cast<const float4*>(anchors)[a];
            const float area_a = (an.z - an.x) * (an.w - an.y);
            float v = -1.f; int vi = 0;
            #pragma unroll
            for (int j = 0; j < NGT; ++j) {
                const float4 tb = tb_s[j];
                const float ltx = fmaxf(tb.x, an.x), lty = fmaxf(tb.y, an.y);
                const float rbx = fminf(tb.z, an.z), rby = fminf(tb.w, an.w);
                const float w = fmaxf(rbx - ltx, 0.f), h = fmaxf(rby - lty, 0.f);
                const float inter = w * h;
                const float iou = inter / (ar_s[j] + area_a - inter);
                // per-anchor argmax over gts: strict >, ascending j -> first max
                if (iou > v) { v = iou; vi = j; }
                // per-gt argmax over anchors: strict >, ascending a -> smallest a
                if (iou > best[j]) { best[j] = iou; bestA[j] = a; }
            }
            gt_ov [(size_t)b * NA + a] = v;
            gt_idx[(size_t)b * NA + a] = vi;
        }
    }

    // per-gt block reduce: pack (iou_bits<<32)|~a, butterfly over 64 lanes,
    // then one global atomicMax per gt per wave (associative -> deterministic).
    #pragma unroll
    for (int j = 0; j < NGT; ++j) {
        unsigned long long p = (best[j] < 0.f) ? 0ULL :
            ((((unsigned long long)__float_as_uint(best[j])) << 32)
             | (unsigned)(~(unsigned)bestA[j]));
        #pragma unroll
        for (int off = 32; off >= 1; off >>= 1) {
            const unsigned long long q = __shfl_xor(p, off);
            p = (q > p) ? q : p;
        }
        if ((tid & 63) == 0 && p)
            atomicMax(&prior_pack[b * NGT + j], p);
    }
}

// ---------------- k2: apply prior scatter (1.99) + forced gt_idx override
__global__ void k2_force(
    const unsigned long long* __restrict__ prior_pack,
    float* __restrict__ gt_ov, int* __restrict__ gt_idx)
{
    const int b = blockIdx.x;
    const int i = threadIdx.x; // 0..31
    __shared__ int pa[NGT];
    const unsigned a = ~(unsigned)(prior_pack[b * NGT + i] & 0xFFFFFFFFULL);
    pa[i] = (int)a;
    __syncthreads();
    int m = i;
    #pragma unroll
    for (int j = 0; j < NGT; ++j)
        if (pa[j] == (int)a && j > m) m = j;
    gt_ov [(size_t)b * NA + a] = 1.99f;
    gt_idx[(size_t)b * NA + a] = m;
}

// ---------------- k3: main loss pass. pred_cs tile staged via LDS with
// coalesced float4 loads; softmax computed single-HBM-pass from LDS.
__global__ __launch_bounds__(256) void k3_loss(
    const float* __restrict__ pred_bbs,   // [B][A][4]
    const float* __restrict__ pred_cs,    // [B][A][C]
    const float* __restrict__ tar_bbs,    // [B][N][4]
    const int*   __restrict__ tar_c,      // [B][N]
    const float* __restrict__ anchors,    // [A][4]
    const float* __restrict__ grid_size,  // [A]
    const float* __restrict__ gt_ov,
    const int*   __restrict__ gt_idx,
    float* __restrict__ loc_part, float* __restrict__ ce_part, int* __restrict__ np_part)
{
    const int b   = blockIdx.y;
    const int c   = blockIdx.x;
    const int tid = threadIdx.x;
    const int a0  = c * TILE3;
    const int rows = (a0 + TILE3 <= NA) ? TILE3 : (NA - a0);

    __shared__ __align__(16) float row_s[TILE3 * NCLS];   // 31104 B
    __shared__ float4 tb_s[NGT];
    __shared__ int    tc_s[NGT];

    if (tid < NGT) {
        tb_s[tid] = reinterpret_cast<const float4*>(tar_bbs)[b * NGT + tid];
        tc_s[tid] = tar_c[b * NGT + tid];
    }

    // coalesced tile load: base float offset (b*NA + a0)*81 and rows*81 are
    // multiples of 4 for TILE3=96 (96*81=7776, tail 92*81=7452).
    {
        const float4* src = reinterpret_cast<const float4*>(
            pred_cs + ((size_t)b * NA + a0) * NCLS);
        float4* dst = reinterpret_cast<float4*>(row_s);
        const int nvec = rows * NCLS / 4;
        for (int t = tid; t < nvec; t += 256) dst[t] = src[t];
    }
    __syncthreads();

    float loc = 0.f, ce = 0.f; int npos = 0;

    if (tid < rows) {
        const int a = a0 + tid;
        const float* row = row_s + tid * NCLS;   // stride 81 (odd) -> no bank conflict

        float mx = row[0];
        #pragma unroll 8
        for (int j = 1; j < NCLS; ++j) mx = fmaxf(mx, row[j]);
        float se = 0.f;
        #pragma unroll 8
        for (int j = 0; j < NCLS; ++j) se += expf(row[j] - mx);
        const float lse = mx + logf(se);

        const float ov = gt_ov [(size_t)b * NA + a];
        const int   gi = gt_idx[(size_t)b * NA + a];
        const bool pos = ov > THR;

        const int label = pos ? tc_s[gi] : 0;
        ce = lse - row[label];

        if (pos) {
            const float4 pb = reinterpret_cast<const float4*>(pred_bbs)[(size_t)b * NA + a];
            const float4 an = reinterpret_cast<const float4*>(anchors)[a];
            const float g = grid_size[a] * 0.5f;
            const float tx = tanhf(pb.x), ty = tanhf(pb.y), tz = tanhf(pb.z), tw = tanhf(pb.w);
            const float ax = an.x + tx * g, ay = an.y + ty * g;
            const float az = an.z + tz * g, aw = an.w + tw * g;
            const float4 mb = tb_s[gi];
            loc = fabsf(ax - mb.x) + fabsf(ay - mb.y) + fabsf(az - mb.z) + fabsf(aw - mb.w);
            npos = 1;
        }
    }

    // block reduce (64-lane wave shuffle, then LDS across 4 waves)
    #pragma unroll
    for (int off = 32; off >= 1; off >>= 1) {
        loc  += __shfl_down(loc,  off);
        ce   += __shfl_down(ce,   off);
        npos += __shfl_down(npos, off);
    }
    __shared__ float lred[4], cred[4];
    __shared__ int   nred[4];
    const int wid = tid >> 6;
    if ((tid & 63) == 0) { lred[wid] = loc; cred[wid] = ce; nred[wid] = npos; }
    __syncthreads();
    if (tid == 0) {
        float L = 0.f, Ce = 0.f; int Np = 0;
        #pragma unroll
        for (int wq = 0; wq < 4; ++wq) { L += lred[wq]; Ce += cred[wq]; Np += nred[wq]; }
        loc_part[b * NC3 + c] = L;
        ce_part [b * NC3 + c] = Ce;
        np_part [b * NC3 + c] = Np;
    }
}

// ---------------- k4: fixed-order final reduction -> scalar
__global__ void k4_final(const float* __restrict__ loc_part,
                         const float* __restrict__ ce_part,
                         const int*   __restrict__ np_part,
                         float* __restrict__ out)
{
    const int t = threadIdx.x; // 64 threads
    float loss = 0.f;
    if (t < BATCH) {
        float L = 0.f, Ce = 0.f; int Np = 0;
        for (int c = 0; c < NC3; ++c) {
            L  += loc_part[t * NC3 + c];
            Ce += ce_part [t * NC3 + c];
            Np += np_part [t * NC3 + c];
        }
        const int denom_i = (Np * 4 > 1) ? Np * 4 : 1;
        loss = L / (float)denom_i + Ce / (float)NA;
    }
    #pragma unroll
    for (int off = 32; off >= 1; off >>= 1) loss += __shfl_down(loss, off);
    if (t == 0) out[0] = loss;
}

extern "C" void kernel_launch(void* const* d_in, const int* in_sizes, int n_in,
                              void* d_out, int out_size, void* d_ws, size_t ws_size,
                              hipStream_t stream) {
    const float* pred_bbs  = (const float*)d_in[0];
    const float* pred_cs   = (const float*)d_in[1];
    const float* tar_bbs   = (const float*)d_in[2];
    const int*   tar_c     = (const int*)  d_in[3];
    const float* anchors   = (const float*)d_in[4];
    const float* grid_size = (const float*)d_in[5];
    float* out = (float*)d_out;

    char* ws = (char*)d_ws;
    float* gt_ov = (float*)ws;                              ws += sizeof(float) * BATCH * NA;
    int*   gt_idx = (int*)ws;                               ws += sizeof(int)   * BATCH * NA;
    unsigned long long* prior = (unsigned long long*)ws;    ws += sizeof(unsigned long long) * BATCH * NGT;
    float* loc_part = (float*)ws;                           ws += sizeof(float) * BATCH * NC3;
    float* ce_part  = (float*)ws;                           ws += sizeof(float) * BATCH * NC3;
    int*   np_part  = (int*)ws;                             ws += sizeof(int)   * BATCH * NC3;

    hipLaunchKernelGGL(k0_init, dim3(4), dim3(256), 0, stream, prior);
    hipLaunchKernelGGL(k1_iou, dim3(CH1, BATCH), dim3(256), 0, stream,
                       tar_bbs, anchors, gt_ov, gt_idx, prior);
    hipLaunchKernelGGL(k2_force, dim3(BATCH), dim3(32), 0, stream,
                       prior, gt_ov, gt_idx);
    hipLaunchKernelGGL(k3_loss, dim3(NC3, BATCH), dim3(256), 0, stream,
                       pred_bbs, pred_cs, tar_bbs, tar_c, anchors, grid_size,
                       gt_ov, gt_idx, loc_part, ce_part, np_part);
    hipLaunchKernelGGL(k4_final, dim3(1), dim3(64), 0, stream,
                       loc_part, ce_part, np_part, out);
}

// Round 4
// 68.863 us; speedup vs baseline: 3.3504x; 1.4752x over previous
//
#include <hip/hip_runtime.h>
#include <cstdint>
#include <cstddef>
#include <math.h>

// Problem constants (match reference)
#define BATCH 32
#define NGT   32
#define NA    8732
#define NCLS  81
#define THR   0.4f

#define K1SPAN 512                       // anchors per k1 block (2 per thread)
#define CH1 ((NA + K1SPAN - 1) / K1SPAN) // 18
#define ROWS3 64                         // k3: rows per block (quad per row)
#define NB3 ((NA + ROWS3 - 1) / ROWS3)   // 137 blocks per image

// ---------------- k1: IoU. Thread owns anchors; gt loop fully unrolled in
// registers. Per-gt best written per-chunk (no atomics, no init kernel).
__global__ __launch_bounds__(256) void k1_iou(
    const float* __restrict__ tar_bbs,   // [B][N][4]
    const float* __restrict__ anchors,   // [A][4]
    float* __restrict__ gt_ov,           // [B][A]
    int*   __restrict__ gt_idx,          // [B][A]
    unsigned long long* __restrict__ chunk_best) // [B][NGT][CH1]
{
    const int b   = blockIdx.y;
    const int c   = blockIdx.x;
    const int tid = threadIdx.x;

    __shared__ float4 tb_s[NGT];
    __shared__ float  ar_s[NGT];
    __shared__ unsigned long long wbest[4][NGT];
    if (tid < NGT) {
        const float4 t = reinterpret_cast<const float4*>(tar_bbs)[b * NGT + tid];
        tb_s[tid] = t;
        ar_s[tid] = (t.z - t.x) * (t.w - t.y);
    }
    __syncthreads();

    float best[NGT];   // per-gt best iou over this thread's anchors
    int   bestA[NGT];
    #pragma unroll
    for (int j = 0; j < NGT; ++j) { best[j] = -1.f; bestA[j] = 0; }

    const int a0 = c * K1SPAN;
    #pragma unroll
    for (int k = 0; k < K1SPAN / 256; ++k) {
        const int a = a0 + k * 256 + tid;
        if (a < NA) {
            const float4 an = reinterpret_cast<const float4*>(anchors)[a];
            const float area_a = (an.z - an.x) * (an.w - an.y);
            float v = -1.f; int vi = 0;
            #pragma unroll
            for (int j = 0; j < NGT; ++j) {
                const float4 tb = tb_s[j];
                const float ltx = fmaxf(tb.x, an.x), lty = fmaxf(tb.y, an.y);
                const float rbx = fminf(tb.z, an.z), rby = fminf(tb.w, an.w);
                const float w = fmaxf(rbx - ltx, 0.f), h = fmaxf(rby - lty, 0.f);
                const float inter = w * h;
                const float iou = inter / (ar_s[j] + area_a - inter);
                // per-anchor argmax over gts: strict >, ascending j -> first max
                if (iou > v) { v = iou; vi = j; }
                // per-gt argmax over anchors: strict >, ascending a -> smallest a
                if (iou > best[j]) { best[j] = iou; bestA[j] = a; }
            }
            gt_ov [(size_t)b * NA + a] = v;
            gt_idx[(size_t)b * NA + a] = vi;
        }
    }

    // per-gt reduce: pack (iou_bits<<32)|~a, 64-lane butterfly, wave leaders
    // stash in LDS, first 32 threads fold 4 waves -> chunk_best.
    const int wid = tid >> 6;
    #pragma unroll
    for (int j = 0; j < NGT; ++j) {
        unsigned long long p = (best[j] < 0.f) ? 0ULL :
            ((((unsigned long long)__float_as_uint(best[j])) << 32)
             | (unsigned)(~(unsigned)bestA[j]));
        #pragma unroll
        for (int off = 32; off >= 1; off >>= 1) {
            const unsigned long long q = __shfl_xor(p, off);
            p = (q > p) ? q : p;
        }
        if ((tid & 63) == 0) wbest[wid][j] = p;
    }
    __syncthreads();
    if (tid < NGT) {
        unsigned long long m = wbest[0][tid];
        #pragma unroll
        for (int w = 1; w < 4; ++w) {
            const unsigned long long q = wbest[w][tid];
            m = (q > m) ? q : m;
        }
        chunk_best[((size_t)b * NGT + tid) * CH1 + c] = m;
    }
}

// ---------------- k2: fold chunks, apply prior scatter (1.99) + forced gt_idx
__global__ void k2_force(
    const unsigned long long* __restrict__ chunk_best,
    float* __restrict__ gt_ov, int* __restrict__ gt_idx)
{
    const int b = blockIdx.x;
    const int i = threadIdx.x; // 0..31
    __shared__ int pa[NGT];
    unsigned long long p = 0ULL;
    for (int c = 0; c < CH1; ++c) {
        const unsigned long long q = chunk_best[((size_t)b * NGT + i) * CH1 + c];
        p = (q > p) ? q : p;
    }
    const unsigned a = ~(unsigned)(p & 0xFFFFFFFFULL);
    pa[i] = (int)a;
    __syncthreads();
    int m = i;
    #pragma unroll
    for (int j = 0; j < NGT; ++j)
        if (pa[j] == (int)a && j > m) m = j;
    gt_ov [(size_t)b * NA + a] = 1.99f;   // same-value races across gts are benign
    gt_idx[(size_t)b * NA + a] = m;
}

// ---------------- k3: main loss. Quad-per-row, row in registers, single HBM
// pass, quad shuffles for max/sum/label-select. No LDS row staging.
__global__ __launch_bounds__(256) void k3_loss(
    const float* __restrict__ pred_bbs,   // [B][A][4]
    const float* __restrict__ pred_cs,    // [B][A][C]
    const float* __restrict__ tar_bbs,    // [B][N][4]
    const int*   __restrict__ tar_c,      // [B][N]
    const float* __restrict__ anchors,    // [A][4]
    const float* __restrict__ grid_size,  // [A]
    const float* __restrict__ gt_ov,
    const int*   __restrict__ gt_idx,
    float* __restrict__ loc_part, float* __restrict__ ce_part, int* __restrict__ np_part)
{
    const int b   = blockIdx.y;
    const int c   = blockIdx.x;
    const int tid = threadIdx.x;
    const int q   = tid >> 2;   // quad id = row within tile
    const int k   = tid & 3;    // lane within quad
    const int a   = c * ROWS3 + q;

    __shared__ float4 tb_s[NGT];
    __shared__ int    tc_s[NGT];
    if (tid < NGT) {
        tb_s[tid] = reinterpret_cast<const float4*>(tar_bbs)[b * NGT + tid];
        tc_s[tid] = tar_c[b * NGT + tid];
    }
    __syncthreads();

    float loc = 0.f, ce = 0.f; int npos = 0;

    if (a < NA) {
        const float* row = pred_cs + ((size_t)b * NA + a) * NCLS;

        // load this lane's strided slice of the row into registers (one pass)
        float vals[21];
        #pragma unroll
        for (int m = 0; m < 21; ++m) {
            const int e = k + 4 * m;
            vals[m] = (e < NCLS) ? row[e] : -INFINITY;
        }

        float mx = vals[0];
        #pragma unroll
        for (int m = 1; m < 21; ++m) mx = fmaxf(mx, vals[m]);
        mx = fmaxf(mx, __shfl_xor(mx, 1));
        mx = fmaxf(mx, __shfl_xor(mx, 2));

        const float ov = gt_ov [(size_t)b * NA + a];
        const int   gi = gt_idx[(size_t)b * NA + a];
        const bool pos = ov > THR;
        const int label = pos ? tc_s[gi] : 0;

        float se = 0.f, sel = 0.f;
        #pragma unroll
        for (int m = 0; m < 21; ++m) {
            const int e = k + 4 * m;
            if (e < NCLS) {
                const float v = vals[m];
                se += expf(v - mx);
                if (e == label) sel = v;
            }
        }
        se  += __shfl_xor(se, 1);  se  += __shfl_xor(se, 2);
        sel += __shfl_xor(sel, 1); sel += __shfl_xor(sel, 2);

        if (k == 0) {
            const float lse = mx + logf(se);
            ce = lse - sel;
            if (pos) {
                const float4 pb = reinterpret_cast<const float4*>(pred_bbs)[(size_t)b * NA + a];
                const float4 an = reinterpret_cast<const float4*>(anchors)[a];
                const float g = grid_size[a] * 0.5f;
                const float tx = tanhf(pb.x), ty = tanhf(pb.y), tz = tanhf(pb.z), tw = tanhf(pb.w);
                const float ax = an.x + tx * g, ay = an.y + ty * g;
                const float az = an.z + tz * g, aw = an.w + tw * g;
                const float4 mb = tb_s[gi];
                loc = fabsf(ax - mb.x) + fabsf(ay - mb.y) + fabsf(az - mb.z) + fabsf(aw - mb.w);
                npos = 1;
            }
        }
    }

    // block reduce: non-quad-leaders hold zeros, so a plain 64-lane down-sum
    // followed by a 4-wave LDS fold is exact.
    #pragma unroll
    for (int off = 32; off >= 1; off >>= 1) {
        loc  += __shfl_down(loc,  off);
        ce   += __shfl_down(ce,   off);
        npos += __shfl_down(npos, off);
    }
    __shared__ float lred[4], cred[4];
    __shared__ int   nred[4];
    const int wid = tid >> 6;
    if ((tid & 63) == 0) { lred[wid] = loc; cred[wid] = ce; nred[wid] = npos; }
    __syncthreads();
    if (tid == 0) {
        float L = 0.f, Ce = 0.f; int Np = 0;
        #pragma unroll
        for (int wq = 0; wq < 4; ++wq) { L += lred[wq]; Ce += cred[wq]; Np += nred[wq]; }
        loc_part[b * NB3 + c] = L;
        ce_part [b * NB3 + c] = Ce;
        np_part [b * NB3 + c] = Np;
    }
}

// ---------------- k4: fixed-order final reduction -> scalar
__global__ void k4_final(const float* __restrict__ loc_part,
                         const float* __restrict__ ce_part,
                         const int*   __restrict__ np_part,
                         float* __restrict__ out)
{
    const int t = threadIdx.x; // 64 threads
    float loss = 0.f;
    if (t < BATCH) {
        float L = 0.f, Ce = 0.f; int Np = 0;
        for (int c = 0; c < NB3; ++c) {
            L  += loc_part[t * NB3 + c];
            Ce += ce_part [t * NB3 + c];
            Np += np_part [t * NB3 + c];
        }
        const int denom_i = (Np * 4 > 1) ? Np * 4 : 1;
        loss = L / (float)denom_i + Ce / (float)NA;
    }
    #pragma unroll
    for (int off = 32; off >= 1; off >>= 1) loss += __shfl_down(loss, off);
    if (t == 0) out[0] = loss;
}

extern "C" void kernel_launch(void* const* d_in, const int* in_sizes, int n_in,
                              void* d_out, int out_size, void* d_ws, size_t ws_size,
                              hipStream_t stream) {
    const float* pred_bbs  = (const float*)d_in[0];
    const float* pred_cs   = (const float*)d_in[1];
    const float* tar_bbs   = (const float*)d_in[2];
    const int*   tar_c     = (const int*)  d_in[3];
    const float* anchors   = (const float*)d_in[4];
    const float* grid_size = (const float*)d_in[5];
    float* out = (float*)d_out;

    char* ws = (char*)d_ws;
    float* gt_ov = (float*)ws;                              ws += sizeof(float) * BATCH * NA;
    int*   gt_idx = (int*)ws;                               ws += sizeof(int)   * BATCH * NA;
    unsigned long long* chunk_best = (unsigned long long*)ws;
    ws += sizeof(unsigned long long) * BATCH * NGT * CH1;
    float* loc_part = (float*)ws;                           ws += sizeof(float) * BATCH * NB3;
    float* ce_part  = (float*)ws;                           ws += sizeof(float) * BATCH * NB3;
    int*   np_part  = (int*)ws;                             ws += sizeof(int)   * BATCH * NB3;

    hipLaunchKernelGGL(k1_iou, dim3(CH1, BATCH), dim3(256), 0, stream,
                       tar_bbs, anchors, gt_ov, gt_idx, chunk_best);
    hipLaunchKernelGGL(k2_force, dim3(BATCH), dim3(32), 0, stream,
                       chunk_best, gt_ov, gt_idx);
    hipLaunchKernelGGL(k3_loss, dim3(NB3, BATCH), dim3(256), 0, stream,
                       pred_bbs, pred_cs, tar_bbs, tar_c, anchors, grid_size,
                       gt_ov, gt_idx, loc_part, ce_part, np_part);
    hipLaunchKernelGGL(k4_final, dim3(1), dim3(64), 0, stream,
                       loc_part, ce_part, np_part, out);
}

// Round 5
// 59.235 us; speedup vs baseline: 3.8950x; 1.1626x over previous
//
#include <hip/hip_runtime.h>
#include <cstdint>
#include <cstddef>
#include <math.h>

// Problem constants (match reference)
#define BATCH 32
#define NGT   32
#define NA    8732
#define NCLS  81
#define THR   0.4f

#define K1SPAN 512                       // anchors per k1 block (2 per thread)
#define CH1 ((NA + K1SPAN - 1) / K1SPAN) // 18
#define ROWS3 64                         // k3: rows per block (quad per row)
#define NB3 ((NA + ROWS3 - 1) / ROWS3)   // 137 blocks per image

#define L2E 1.4426950408889634f
#define LN2 0.6931471805599453f

// ---------------- k1: IoU. Thread owns anchors; gt loop fully unrolled in
// registers. Per-gt best written per-chunk (no atomics, no init kernel).
__global__ __launch_bounds__(256) void k1_iou(
    const float* __restrict__ tar_bbs,   // [B][N][4]
    const float* __restrict__ anchors,   // [A][4]
    float* __restrict__ gt_ov,           // [B][A]
    int*   __restrict__ gt_idx,          // [B][A]
    unsigned long long* __restrict__ chunk_best) // [B][NGT][CH1]
{
    const int b   = blockIdx.y;
    const int c   = blockIdx.x;
    const int tid = threadIdx.x;

    __shared__ float4 tb_s[NGT];
    __shared__ float  ar_s[NGT];
    __shared__ unsigned long long wbest[4][NGT];
    if (tid < NGT) {
        const float4 t = reinterpret_cast<const float4*>(tar_bbs)[b * NGT + tid];
        tb_s[tid] = t;
        ar_s[tid] = (t.z - t.x) * (t.w - t.y);
    }
    __syncthreads();

    float best[NGT];   // per-gt best iou over this thread's anchors
    int   bestA[NGT];
    #pragma unroll
    for (int j = 0; j < NGT; ++j) { best[j] = -1.f; bestA[j] = 0; }

    const int a0 = c * K1SPAN;
    #pragma unroll
    for (int k = 0; k < K1SPAN / 256; ++k) {
        const int a = a0 + k * 256 + tid;
        if (a < NA) {
            const float4 an = reinterpret_cast<const float4*>(anchors)[a];
            const float area_a = (an.z - an.x) * (an.w - an.y);
            float v = -1.f; int vi = 0;
            #pragma unroll
            for (int j = 0; j < NGT; ++j) {
                const float4 tb = tb_s[j];
                const float ltx = fmaxf(tb.x, an.x), lty = fmaxf(tb.y, an.y);
                const float rbx = fminf(tb.z, an.z), rby = fminf(tb.w, an.w);
                const float w = fmaxf(rbx - ltx, 0.f), h = fmaxf(rby - lty, 0.f);
                const float inter = w * h;
                const float iou = inter / (ar_s[j] + area_a - inter);
                // per-anchor argmax over gts: strict >, ascending j -> first max
                if (iou > v) { v = iou; vi = j; }
                // per-gt argmax over anchors: strict >, ascending a -> smallest a
                if (iou > best[j]) { best[j] = iou; bestA[j] = a; }
            }
            gt_ov [(size_t)b * NA + a] = v;
            gt_idx[(size_t)b * NA + a] = vi;
        }
    }

    // per-gt reduce: pack (iou_bits<<32)|~a, 64-lane butterfly, wave leaders
    // stash in LDS, first 32 threads fold 4 waves -> chunk_best.
    const int wid = tid >> 6;
    #pragma unroll
    for (int j = 0; j < NGT; ++j) {
        unsigned long long p = (best[j] < 0.f) ? 0ULL :
            ((((unsigned long long)__float_as_uint(best[j])) << 32)
             | (unsigned)(~(unsigned)bestA[j]));
        #pragma unroll
        for (int off = 32; off >= 1; off >>= 1) {
            const unsigned long long q = __shfl_xor(p, off);
            p = (q > p) ? q : p;
        }
        if ((tid & 63) == 0) wbest[wid][j] = p;
    }
    __syncthreads();
    if (tid < NGT) {
        unsigned long long m = wbest[0][tid];
        #pragma unroll
        for (int w = 1; w < 4; ++w) {
            const unsigned long long q = wbest[w][tid];
            m = (q > m) ? q : m;
        }
        chunk_best[((size_t)b * NGT + tid) * CH1 + c] = m;
    }
}

// ---------------- k2: fold chunks (8 lanes per gt), apply prior scatter
// (1.99) + forced gt_idx override.
__global__ __launch_bounds__(256) void k2_force(
    const unsigned long long* __restrict__ chunk_best,
    float* __restrict__ gt_ov, int* __restrict__ gt_idx)
{
    const int b  = blockIdx.x;
    const int t  = threadIdx.x;
    const int gt = t >> 3;     // 0..31
    const int l8 = t & 7;      // lane within 8-group
    __shared__ int pa[NGT];

    unsigned long long p = 0ULL;
    #pragma unroll
    for (int kk = 0; kk < 3; ++kk) {
        const int c = l8 + 8 * kk;
        if (c < CH1) {
            const unsigned long long q = chunk_best[((size_t)b * NGT + gt) * CH1 + c];
            p = (q > p) ? q : p;
        }
    }
    #pragma unroll
    for (int off = 4; off >= 1; off >>= 1) {
        const unsigned long long q = __shfl_xor(p, off);
        p = (q > p) ? q : p;
    }
    if (l8 == 0) pa[gt] = (int)(~(unsigned)(p & 0xFFFFFFFFULL));
    __syncthreads();

    if (t < NGT) {
        const int a = pa[t];
        int m = t;
        #pragma unroll
        for (int j = 0; j < NGT; ++j)
            if (pa[j] == a && j > m) m = j;
        gt_ov [(size_t)b * NA + a] = 1.99f;   // same-value races across gts are benign
        gt_idx[(size_t)b * NA + a] = m;
    }
}

// ---------------- k3: main loss. Quad-per-row, row in registers, single HBM
// pass, exp2-based LSE, quad shuffles for max/sum/label-select.
__global__ __launch_bounds__(256) void k3_loss(
    const float* __restrict__ pred_bbs,   // [B][A][4]
    const float* __restrict__ pred_cs,    // [B][A][C]
    const float* __restrict__ tar_bbs,    // [B][N][4]
    const int*   __restrict__ tar_c,      // [B][N]
    const float* __restrict__ anchors,    // [A][4]
    const float* __restrict__ grid_size,  // [A]
    const float* __restrict__ gt_ov,
    const int*   __restrict__ gt_idx,
    float* __restrict__ loc_part, float* __restrict__ ce_part, int* __restrict__ np_part)
{
    const int b   = blockIdx.y;
    const int c   = blockIdx.x;
    const int tid = threadIdx.x;
    const int q   = tid >> 2;   // quad id = row within tile
    const int k   = tid & 3;    // lane within quad
    const int a   = c * ROWS3 + q;

    __shared__ float4 tb_s[NGT];
    __shared__ int    tc_s[NGT];
    if (tid < NGT) {
        tb_s[tid] = reinterpret_cast<const float4*>(tar_bbs)[b * NGT + tid];
        tc_s[tid] = tar_c[b * NGT + tid];
    }
    __syncthreads();

    float loc = 0.f, ce = 0.f; int npos = 0;

    if (a < NA) {
        const float* row = pred_cs + ((size_t)b * NA + a) * NCLS + k;

        // one HBM pass: lane k holds elements k, k+4, ..., k+80
        float vals[21];
        #pragma unroll
        for (int m = 0; m < 20; ++m) vals[m] = row[4 * m];
        vals[20] = (k == 0) ? row[80] : -INFINITY;

        float mx = vals[0];
        #pragma unroll
        for (int m = 1; m < 21; ++m) mx = fmaxf(mx, vals[m]);
        mx = fmaxf(mx, __shfl_xor(mx, 1));
        mx = fmaxf(mx, __shfl_xor(mx, 2));

        const float ov = gt_ov [(size_t)b * NA + a];
        const int   gi = gt_idx[(size_t)b * NA + a];
        const bool pos = ov > THR;
        const int label = pos ? tc_s[gi] : 0;

        float se = 0.f, sel = 0.f;
        #pragma unroll
        for (int m = 0; m < 21; ++m) {
            const float v = vals[m];
            se += exp2f((v - mx) * L2E);   // -inf pad contributes exactly 0
            if (k + 4 * m == label) sel = v;
        }
        se  += __shfl_xor(se, 1);  se  += __shfl_xor(se, 2);
        sel += __shfl_xor(sel, 1); sel += __shfl_xor(sel, 2);

        if (k == 0) {
            const float lse = mx + LN2 * log2f(se);
            ce = lse - sel;
            if (pos) {
                const float4 pb = reinterpret_cast<const float4*>(pred_bbs)[(size_t)b * NA + a];
                const float4 an = reinterpret_cast<const float4*>(anchors)[a];
                const float g = grid_size[a] * 0.5f;
                const float tx = tanhf(pb.x), ty = tanhf(pb.y), tz = tanhf(pb.z), tw = tanhf(pb.w);
                const float ax = an.x + tx * g, ay = an.y + ty * g;
                const float az = an.z + tz * g, aw = an.w + tw * g;
                const float4 mb = tb_s[gi];
                loc = fabsf(ax - mb.x) + fabsf(ay - mb.y) + fabsf(az - mb.z) + fabsf(aw - mb.w);
                npos = 1;
            }
        }
    }

    // block reduce: non-quad-leaders hold zeros, plain 64-lane down-sum then
    // 4-wave LDS fold.
    #pragma unroll
    for (int off = 32; off >= 1; off >>= 1) {
        loc  += __shfl_down(loc,  off);
        ce   += __shfl_down(ce,   off);
        npos += __shfl_down(npos, off);
    }
    __shared__ float lred[4], cred[4];
    __shared__ int   nred[4];
    const int wid = tid >> 6;
    if ((tid & 63) == 0) { lred[wid] = loc; cred[wid] = ce; nred[wid] = npos; }
    __syncthreads();
    if (tid == 0) {
        float L = 0.f, Ce = 0.f; int Np = 0;
        #pragma unroll
        for (int wq = 0; wq < 4; ++wq) { L += lred[wq]; Ce += cred[wq]; Np += nred[wq]; }
        loc_part[b * NB3 + c] = L;
        ce_part [b * NB3 + c] = Ce;
        np_part [b * NB3 + c] = Np;
    }
}

// ---------------- k4: parallel final reduction -> scalar.
// 1024 threads: 32 lanes per image, strided chunk loads, shuffle reduce.
__global__ __launch_bounds__(1024) void k4_final(
    const float* __restrict__ loc_part,
    const float* __restrict__ ce_part,
    const int*   __restrict__ np_part,
    float* __restrict__ out)
{
    const int t   = threadIdx.x;
    const int img = t >> 5;    // 0..31
    const int l   = t & 31;

    float L = 0.f, Ce = 0.f; int Np = 0;
    #pragma unroll
    for (int kk = 0; kk < 5; ++kk) {
        const int c = l + 32 * kk;
        if (c < NB3) {
            L  += loc_part[img * NB3 + c];
            Ce += ce_part [img * NB3 + c];
            Np += np_part [img * NB3 + c];
        }
    }
    #pragma unroll
    for (int off = 16; off >= 1; off >>= 1) {
        L  += __shfl_xor(L,  off);
        Ce += __shfl_xor(Ce, off);
        Np += __shfl_xor(Np, off);
    }

    __shared__ float sloss[BATCH];
    if (l == 0) {
        const int denom_i = (Np * 4 > 1) ? Np * 4 : 1;
        sloss[img] = L / (float)denom_i + Ce / (float)NA;
    }
    __syncthreads();
    if (t == 0) {
        float loss = 0.f;
        #pragma unroll
        for (int i = 0; i < BATCH; ++i) loss += sloss[i];
        out[0] = loss;
    }
}

extern "C" void kernel_launch(void* const* d_in, const int* in_sizes, int n_in,
                              void* d_out, int out_size, void* d_ws, size_t ws_size,
                              hipStream_t stream) {
    const float* pred_bbs  = (const float*)d_in[0];
    const float* pred_cs   = (const float*)d_in[1];
    const float* tar_bbs   = (const float*)d_in[2];
    const int*   tar_c     = (const int*)  d_in[3];
    const float* anchors   = (const float*)d_in[4];
    const float* grid_size = (const float*)d_in[5];
    float* out = (float*)d_out;

    char* ws = (char*)d_ws;
    float* gt_ov = (float*)ws;                              ws += sizeof(float) * BATCH * NA;
    int*   gt_idx = (int*)ws;                               ws += sizeof(int)   * BATCH * NA;
    unsigned long long* chunk_best = (unsigned long long*)ws;
    ws += sizeof(unsigned long long) * BATCH * NGT * CH1;
    float* loc_part = (float*)ws;                           ws += sizeof(float) * BATCH * NB3;
    float* ce_part  = (float*)ws;                           ws += sizeof(float) * BATCH * NB3;
    int*   np_part  = (int*)ws;                             ws += sizeof(int)   * BATCH * NB3;

    hipLaunchKernelGGL(k1_iou, dim3(CH1, BATCH), dim3(256), 0, stream,
                       tar_bbs, anchors, gt_ov, gt_idx, chunk_best);
    hipLaunchKernelGGL(k2_force, dim3(BATCH), dim3(256), 0, stream,
                       chunk_best, gt_ov, gt_idx);
    hipLaunchKernelGGL(k3_loss, dim3(NB3, BATCH), dim3(256), 0, stream,
                       pred_bbs, pred_cs, tar_bbs, tar_c, anchors, grid_size,
                       gt_ov, gt_idx, loc_part, ce_part, np_part);
    hipLaunchKernelGGL(k4_final, dim3(1), dim3(1024), 0, stream,
                       loc_part, ce_part, np_part, out);
}